// Round 3
// baseline (267.544 us; speedup 1.0000x reference)
//
#include <hip/hip_runtime.h>
#include <math.h>

#define NQ    14
#define DIM   16384
#define DEPTH 4

typedef float2 c32;

__device__ __forceinline__ c32 cmul(c32 a, c32 b) {
    return make_float2(a.x*b.x - a.y*b.y, a.x*b.y + a.y*b.x);
}
__device__ __forceinline__ c32 cadd(c32 a, c32 b) { return make_float2(a.x+b.x, a.y+b.y); }
__device__ __forceinline__ c32 csc(float s, c32 a) { return make_float2(s*a.x, s*a.y); }

// LDS swizzle: bank-pair (b64) = sw(e)&15 = e[3:0] ^ e[9:6]. Pass mappings below
// are chosen so all 64 lanes spread uniformly over 16 bank pairs (4 lanes/pair).
__device__ __forceinline__ int sw(int e) { return e ^ ((e >> 6) & 0xF); }

// CZ chain sign: qubit w <-> flat bit (13-w); adjacent qubit pairs are adjacent
// flat bits, so parity = popc(e & (e>>1)) & 1.
__device__ __forceinline__ float czsgn(int e) {
    return (__popc(e & (e >> 1)) & 1) ? -1.0f : 1.0f;
}

// 3-qubit passes (spill avoidance: only 8 amps = 16 VGPRs live, vs 16 amps = 32
// VGPRs which spilled to scratch at the 64-VGPR cap the backend pins for
// 1024-thread workgroups — round 1/2: 450 MB HBM scratch traffic).
// Thread t (10b), seq group s, group-local l (3b; 2b for pass 4):
// P0: gates q0-2   e[13:11]=l, e[10]=s,  e[9:0]=t
// P1: gates q3-5   e[13]=s, e[12:11]=t[9:8], e[10:8]=l, e[7:0]=t[7:0]
// P2: gates q6-8   e[13]=s, e[12:8]=t[9:5],  e[7:5]=l,  e[4:0]=t[4:0]
// P3: gates q9-11  e[13]=s, e[12:10]=t[9:7], e[9:6]=t[5:2], e[5]=t[6], e[4:2]=l, e[1:0]=t[1:0]
// P4: gates q12,13 e[13:12]=s, e[11:2]=t, e[1:0]=l
template<int PASS>
__device__ __forceinline__ int emap3(int t, int s, int l) {
    if (PASS == 0) return (l << 11) | (s << 10) | t;
    if (PASS == 1) return (s << 13) | ((t >> 8) << 11) | (l << 8) | (t & 255);
    if (PASS == 2) return (s << 13) | ((t >> 5) << 8) | (l << 5) | (t & 31);
    if (PASS == 3) return (s << 13) | ((t >> 7) << 10) | (((t >> 2) & 15) << 6)
                        | (((t >> 6) & 1) << 5) | (l << 2) | (t & 3);
    return (s << 12) | (t << 2) | l;
}

template<int PASS>
__device__ __forceinline__ void do_pass(c32* st, const c32 (*gl)[4], int t,
                                        bool mulsign, bool finalp, float* acc)
{
    constexpr int NS    = (PASS == 4) ? 4 : 2;   // sequential groups
    constexpr int NL    = (PASS == 4) ? 4 : 8;   // amps per group
    constexpr int NG    = (PASS == 4) ? 2 : 3;   // gates this pass
    constexpr int QBASE = (PASS == 4) ? 12 : 3 * PASS;

    // hoist wave-uniform gate matrices (broadcast LDS reads, done once)
    c32 u[NG][4];
    #pragma unroll
    for (int g = 0; g < NG; ++g) {
        u[g][0] = gl[QBASE + g][0]; u[g][1] = gl[QBASE + g][1];
        u[g][2] = gl[QBASE + g][2]; u[g][3] = gl[QBASE + g][3];
    }

    #pragma unroll 1   // keep groups sequential: only 8 amps live at a time
    for (int s = 0; s < NS; ++s) {
        c32 a[NL];
        #pragma unroll
        for (int l = 0; l < NL; ++l)
            a[l] = st[sw(emap3<PASS>(t, s, l))];
        if (mulsign) {  // fused CZ sign from the previous layer
            #pragma unroll
            for (int l = 0; l < NL; ++l) {
                float sg = czsgn(emap3<PASS>(t, s, l));
                a[l].x *= sg; a[l].y *= sg;
            }
        }
        #pragma unroll
        for (int g = 0; g < NG; ++g) {
            const int mask = (PASS == 4) ? (2 >> g) : (4 >> g);
            #pragma unroll
            for (int l = 0; l < NL; ++l) {
                if (l & mask) continue;
                const int j = l | mask;
                c32 x = a[l], y = a[j];
                a[l] = cadd(cmul(u[g][0], x), cmul(u[g][1], y));
                a[j] = cadd(cmul(u[g][2], x), cmul(u[g][3], y));
            }
        }
        if (!finalp) {
            #pragma unroll
            for (int l = 0; l < NL; ++l)
                st[sw(emap3<PASS>(t, s, l))] = a[l];
        } else {
            // fused probability reduction: acc[w] += ±|a|^2 per Z_SIGNS
            #pragma unroll
            for (int l = 0; l < NL; ++l) {
                int e = emap3<PASS>(t, s, l);
                float p = a[l].x*a[l].x + a[l].y*a[l].y;
                #pragma unroll
                for (int w = 0; w < NQ; ++w)
                    acc[w] += ((e >> (13 - w)) & 1) ? -p : p;
            }
        }
    }
}

__device__ __forceinline__ void do_layer(c32* st, const c32 (*gl)[4], int t,
                                         bool mulsign)
{
    do_pass<0>(st, gl, t, mulsign, false, nullptr); __syncthreads();
    do_pass<1>(st, gl, t, false,   false, nullptr); __syncthreads();
    do_pass<2>(st, gl, t, false,   false, nullptr); __syncthreads();
    do_pass<3>(st, gl, t, false,   false, nullptr); __syncthreads();
    do_pass<4>(st, gl, t, false,   false, nullptr); __syncthreads();
}

__global__ __launch_bounds__(1024)
void qlg_kernel(const float* __restrict__ cond,
                const float* __restrict__ Wenc,
                const float* __restrict__ benc,
                const float* __restrict__ wts,
                float* __restrict__ out)
{
    __shared__ c32 st[DIM];                 // 128 KB state (swizzled index)
    __shared__ c32 gates[DEPTH][NQ][4];     // variational 2x2 gate matrices
    __shared__ c32 qv[NQ][2];               // per-wire product-state vectors
    __shared__ c32 Phi[128];                // partial product, qubits 0..6
    __shared__ c32 Plo[128];                // partial product, qubits 7..13
    __shared__ float embS[NQ];
    __shared__ float wred[16][NQ];
    __shared__ float lat[NQ];

    const int b = blockIdx.x;
    const int t = threadIdx.x;

    // ---- stage 1: embedding (SiLU) + gate matrices ----
    if (t < NQ) {
        float s = benc[t];
        #pragma unroll
        for (int k = 0; k < NQ; ++k) s += cond[b*NQ + k] * Wenc[t*NQ + k];
        embS[t] = s / (1.0f + __expf(-s));
    }
    if (t >= 64 && t < 64 + DEPTH*NQ) {
        const int gi = t - 64;
        const int d = gi / NQ, w = gi % NQ;
        const float p0 = wts[(d*NQ + w)*3 + 0];
        const float p1 = wts[(d*NQ + w)*3 + 1];
        const float p2 = wts[(d*NQ + w)*3 + 2];
        float s0, c0, s1, c1, s2, c2;
        sincosf(0.5f*p0, &s0, &c0);
        sincosf(0.5f*p1, &s1, &c1);
        sincosf(0.5f*p2, &s2, &c2);
        // U = RY(p2) * RX(p1) * RZ(p0)
        c32 e0  = make_float2(c0, -s0);     // exp(-i p0/2)
        c32 e0c = make_float2(c0,  s0);
        c32 is1 = make_float2(0.f, -s1);    // -i sin(p1/2)
        c32 m00 = csc(c1, e0);
        c32 m01 = cmul(is1, e0c);
        c32 m10 = cmul(is1, e0);
        c32 m11 = csc(c1, e0c);
        gates[d][w][0] = cadd(csc(c2, m00), csc(-s2, m10));
        gates[d][w][1] = cadd(csc(c2, m01), csc(-s2, m11));
        gates[d][w][2] = cadd(csc(s2, m00), csc( c2, m10));
        gates[d][w][3] = cadd(csc(s2, m01), csc( c2, m11));
    }
    __syncthreads();

    // ---- stage 2: per-wire 2-vectors after encoding + layer 0 ----
    if (t < NQ) {
        float v = embS[t];
        float s, c;
        sincosf(0.5f*v, &s, &c);
        c32 a0 = make_float2(c*c,  s*s);    // (RY RX)|0> component 0
        c32 a1 = make_float2(s*c, -s*c);    // component 1
        c32 u00 = gates[0][t][0], u01 = gates[0][t][1];
        c32 u10 = gates[0][t][2], u11 = gates[0][t][3];
        qv[t][0] = cadd(cmul(u00, a0), cmul(u01, a1));
        qv[t][1] = cadd(cmul(u10, a0), cmul(u11, a1));
    }
    __syncthreads();

    // ---- stage 3: partial-product tables ----
    if (t < 128) {
        c32 p = qv[0][(t >> 6) & 1];
        #pragma unroll
        for (int w = 1; w <= 6; ++w) p = cmul(p, qv[w][(t >> (6 - w)) & 1]);
        Phi[t] = p;
    } else if (t < 256) {
        const int j = t - 128;
        c32 p = qv[7][(j >> 6) & 1];
        #pragma unroll
        for (int w = 8; w <= 13; ++w) p = cmul(p, qv[w][(j >> (13 - w)) & 1]);
        Plo[j] = p;
    }
    __syncthreads();

    // ---- stage 4: build product state, fusing CZ after layer 0 ----
    #pragma unroll
    for (int l = 0; l < 16; ++l) {
        const int e = (l << 10) | t;
        c32 v = cmul(Phi[e >> 7], Plo[e & 127]);
        st[sw(e)] = csc(czsgn(e), v);
    }
    __syncthreads();

    // ---- stage 5: layers 1..3 (layer-3 CZ dropped: |psi|^2 invariant) ----
    do_layer(st, gates[1], t, false);   // CZ after layer 0 fused in build
    do_layer(st, gates[2], t, true);    // CZ after layer 1 fused into load
    // layer 3: last pass fuses the probability reduction (no writeback)
    {
        const c32 (*gl)[4] = gates[3];
        do_pass<0>(st, gl, t, true,  false, nullptr); __syncthreads();
        do_pass<1>(st, gl, t, false, false, nullptr); __syncthreads();
        do_pass<2>(st, gl, t, false, false, nullptr); __syncthreads();
        do_pass<3>(st, gl, t, false, false, nullptr); __syncthreads();
        float acc[NQ];
        #pragma unroll
        for (int w = 0; w < NQ; ++w) acc[w] = 0.f;
        do_pass<4>(st, gl, t, false, true, acc);

        // ---- stage 6: reduce to 14 expectations, layernorm ----
        #pragma unroll
        for (int w = 0; w < NQ; ++w) {
            float v = acc[w];
            #pragma unroll
            for (int off = 32; off > 0; off >>= 1) v += __shfl_down(v, off, 64);
            acc[w] = v;
        }
        const int lane = t & 63, wv = t >> 6;
        if (lane == 0) {
            #pragma unroll
            for (int w = 0; w < NQ; ++w) wred[wv][w] = acc[w];
        }
    }
    __syncthreads();
    if (t < NQ) {
        float s = 0.f;
        #pragma unroll
        for (int k = 0; k < 16; ++k) s += wred[k][t];
        lat[t] = s;
    }
    __syncthreads();
    if (t < NQ) {
        float mu = 0.f;
        #pragma unroll
        for (int k = 0; k < NQ; ++k) mu += lat[k];
        mu *= (1.0f / NQ);
        float var = 0.f;
        #pragma unroll
        for (int k = 0; k < NQ; ++k) { float dv = lat[k] - mu; var += dv*dv; }
        var *= (1.0f / NQ);
        out[b*NQ + t] = (lat[t] - mu) * rsqrtf(var + 1e-5f);
    }
}

extern "C" void kernel_launch(void* const* d_in, const int* in_sizes, int n_in,
                              void* d_out, int out_size, void* d_ws, size_t ws_size,
                              hipStream_t stream)
{
    (void)n_in; (void)d_ws; (void)ws_size; (void)out_size;
    const float* cond = (const float*)d_in[0];
    const float* Wenc = (const float*)d_in[1];
    const float* benc = (const float*)d_in[2];
    const float* wts  = (const float*)d_in[3];
    float* out = (float*)d_out;
    const int B = in_sizes[0] / NQ;   // 256
    qlg_kernel<<<dim3(B), dim3(1024), 0, stream>>>(cond, Wenc, benc, wts, out);
}

// Round 4
// 138.666 us; speedup vs baseline: 1.9294x; 1.9294x over previous
//
#include <hip/hip_runtime.h>
#include <math.h>

#define NQ    14
#define DIM   16384
#define DEPTH 4

typedef float2 c32;

__device__ __forceinline__ c32 cmul(c32 a, c32 b) {
    return make_float2(a.x*b.x - a.y*b.y, a.x*b.y + a.y*b.x);
}
__device__ __forceinline__ c32 cadd(c32 a, c32 b) { return make_float2(a.x+b.x, a.y+b.y); }
__device__ __forceinline__ c32 csc(float s, c32 a) { return make_float2(s*a.x, s*a.y); }

// LDS swizzle: bank-pair (b64) = sw(e)&15 = e[3:0] ^ e[9:6]. Pass mappings below
// are chosen so all 64 lanes spread uniformly over 16 bank pairs (4 lanes/pair).
__device__ __forceinline__ int sw(int e) { return e ^ ((e >> 6) & 0xF); }

// CZ chain sign: qubit w <-> flat bit (13-w); adjacent qubit pairs are adjacent
// flat bits, so parity = popc(e & (e>>1)) & 1.
__device__ __forceinline__ float czsgn(int e) {
    return (__popc(e & (e >> 1)) & 1) ? -1.0f : 1.0f;
}

// 3-qubit passes. Thread t (10b), seq group s, group-local l (3b; 2b for pass 4):
// P0: gates q0-2   e[13:11]=l, e[10]=s,  e[9:0]=t
// P1: gates q3-5   e[13]=s, e[12:11]=t[9:8], e[10:8]=l, e[7:0]=t[7:0]
// P2: gates q6-8   e[13]=s, e[12:8]=t[9:5],  e[7:5]=l,  e[4:0]=t[4:0]
// P3: gates q9-11  e[13]=s, e[12:10]=t[9:7], e[9:6]=t[5:2], e[5]=t[6], e[4:2]=l, e[1:0]=t[1:0]
// P4: gates q12,13 e[13:12]=s, e[11:2]=t, e[1:0]=l
template<int PASS>
__device__ __forceinline__ int emap3(int t, int s, int l) {
    if (PASS == 0) return (l << 11) | (s << 10) | t;
    if (PASS == 1) return (s << 13) | ((t >> 8) << 11) | (l << 8) | (t & 255);
    if (PASS == 2) return (s << 13) | ((t >> 5) << 8) | (l << 5) | (t & 31);
    if (PASS == 3) return (s << 13) | ((t >> 7) << 10) | (((t >> 2) & 15) << 6)
                        | (((t >> 6) & 1) << 5) | (l << 2) | (t & 3);
    return (s << 12) | (t << 2) | l;
}

// Register budget: the backend pins this kernel at 64 VGPRs (launch_bounds and
// waves_per_eu both ignored, rounds 1-3). Round 3 spilled because the hoisted
// gate-matrix array (24 VGPRs) + amp array + addresses exceeded 64. Fix: read
// gate entries from LDS at point of use (wave-uniform broadcast ds_read, ~free;
// st-store aliasing prevents the compiler from re-hoisting them across the
// pass). Peak live set ~40 VGPRs.
template<int PASS>
__device__ __forceinline__ void do_pass(c32* st, const c32 (*gl)[4], int t,
                                        bool mulsign, bool finalp, float* acc)
{
    constexpr int NS    = (PASS == 4) ? 4 : 2;   // sequential groups
    constexpr int NL    = (PASS == 4) ? 4 : 8;   // amps per group
    constexpr int NG    = (PASS == 4) ? 2 : 3;   // gates this pass
    constexpr int QBASE = (PASS == 4) ? 12 : 3 * PASS;

    #pragma unroll 1   // keep groups sequential: only NL amps live at a time
    for (int s = 0; s < NS; ++s) {
        c32 a[NL];
        #pragma unroll
        for (int l = 0; l < NL; ++l)
            a[l] = st[sw(emap3<PASS>(t, s, l))];
        if (mulsign) {  // fused CZ sign from the previous layer
            #pragma unroll
            for (int l = 0; l < NL; ++l) {
                float sg = czsgn(emap3<PASS>(t, s, l));
                a[l].x *= sg; a[l].y *= sg;
            }
        }
        #pragma unroll
        for (int g = 0; g < NG; ++g) {
            const int mask = (PASS == 4) ? (2 >> g) : (4 >> g);
            // gate entries fetched from LDS here (8 VGPRs, live for one gate)
            c32 u00 = gl[QBASE + g][0];
            c32 u01 = gl[QBASE + g][1];
            c32 u10 = gl[QBASE + g][2];
            c32 u11 = gl[QBASE + g][3];
            #pragma unroll
            for (int l = 0; l < NL; ++l) {
                if (l & mask) continue;
                const int j = l | mask;
                c32 x = a[l], y = a[j];
                a[l] = cadd(cmul(u00, x), cmul(u01, y));
                a[j] = cadd(cmul(u10, x), cmul(u11, y));
            }
        }
        if (!finalp) {
            #pragma unroll
            for (int l = 0; l < NL; ++l)
                st[sw(emap3<PASS>(t, s, l))] = a[l];
        } else {
            // fused probability reduction: acc[w] += ±|a|^2 per Z_SIGNS
            #pragma unroll
            for (int l = 0; l < NL; ++l) {
                int e = emap3<PASS>(t, s, l);
                float p = a[l].x*a[l].x + a[l].y*a[l].y;
                #pragma unroll
                for (int w = 0; w < NQ; ++w)
                    acc[w] += ((e >> (13 - w)) & 1) ? -p : p;
            }
        }
    }
}

__device__ __forceinline__ void do_layer(c32* st, const c32 (*gl)[4], int t,
                                         bool mulsign)
{
    do_pass<0>(st, gl, t, mulsign, false, nullptr); __syncthreads();
    do_pass<1>(st, gl, t, false,   false, nullptr); __syncthreads();
    do_pass<2>(st, gl, t, false,   false, nullptr); __syncthreads();
    do_pass<3>(st, gl, t, false,   false, nullptr); __syncthreads();
    do_pass<4>(st, gl, t, false,   false, nullptr); __syncthreads();
}

__global__ __launch_bounds__(1024)
__attribute__((amdgpu_num_vgpr(128)))
void qlg_kernel(const float* __restrict__ cond,
                const float* __restrict__ Wenc,
                const float* __restrict__ benc,
                const float* __restrict__ wts,
                float* __restrict__ out)
{
    __shared__ c32 st[DIM];                 // 128 KB state (swizzled index)
    __shared__ c32 gates[DEPTH][NQ][4];     // variational 2x2 gate matrices
    __shared__ c32 qv[NQ][2];               // per-wire product-state vectors
    __shared__ c32 Phi[128];                // partial product, qubits 0..6
    __shared__ c32 Plo[128];                // partial product, qubits 7..13
    __shared__ float embS[NQ];
    __shared__ float wred[16][NQ];
    __shared__ float lat[NQ];

    const int b = blockIdx.x;
    const int t = threadIdx.x;

    // ---- stage 1: embedding (SiLU) + gate matrices ----
    if (t < NQ) {
        float s = benc[t];
        #pragma unroll
        for (int k = 0; k < NQ; ++k) s += cond[b*NQ + k] * Wenc[t*NQ + k];
        embS[t] = s / (1.0f + __expf(-s));
    }
    if (t >= 64 && t < 64 + DEPTH*NQ) {
        const int gi = t - 64;
        const int d = gi / NQ, w = gi % NQ;
        const float p0 = wts[(d*NQ + w)*3 + 0];
        const float p1 = wts[(d*NQ + w)*3 + 1];
        const float p2 = wts[(d*NQ + w)*3 + 2];
        float s0, c0, s1, c1, s2, c2;
        sincosf(0.5f*p0, &s0, &c0);
        sincosf(0.5f*p1, &s1, &c1);
        sincosf(0.5f*p2, &s2, &c2);
        // U = RY(p2) * RX(p1) * RZ(p0)
        c32 e0  = make_float2(c0, -s0);     // exp(-i p0/2)
        c32 e0c = make_float2(c0,  s0);
        c32 is1 = make_float2(0.f, -s1);    // -i sin(p1/2)
        c32 m00 = csc(c1, e0);
        c32 m01 = cmul(is1, e0c);
        c32 m10 = cmul(is1, e0);
        c32 m11 = csc(c1, e0c);
        gates[d][w][0] = cadd(csc(c2, m00), csc(-s2, m10));
        gates[d][w][1] = cadd(csc(c2, m01), csc(-s2, m11));
        gates[d][w][2] = cadd(csc(s2, m00), csc( c2, m10));
        gates[d][w][3] = cadd(csc(s2, m01), csc( c2, m11));
    }
    __syncthreads();

    // ---- stage 2: per-wire 2-vectors after encoding + layer 0 ----
    if (t < NQ) {
        float v = embS[t];
        float s, c;
        sincosf(0.5f*v, &s, &c);
        c32 a0 = make_float2(c*c,  s*s);    // (RY RX)|0> component 0
        c32 a1 = make_float2(s*c, -s*c);    // component 1
        c32 u00 = gates[0][t][0], u01 = gates[0][t][1];
        c32 u10 = gates[0][t][2], u11 = gates[0][t][3];
        qv[t][0] = cadd(cmul(u00, a0), cmul(u01, a1));
        qv[t][1] = cadd(cmul(u10, a0), cmul(u11, a1));
    }
    __syncthreads();

    // ---- stage 3: partial-product tables ----
    if (t < 128) {
        c32 p = qv[0][(t >> 6) & 1];
        #pragma unroll
        for (int w = 1; w <= 6; ++w) p = cmul(p, qv[w][(t >> (6 - w)) & 1]);
        Phi[t] = p;
    } else if (t < 256) {
        const int j = t - 128;
        c32 p = qv[7][(j >> 6) & 1];
        #pragma unroll
        for (int w = 8; w <= 13; ++w) p = cmul(p, qv[w][(j >> (13 - w)) & 1]);
        Plo[j] = p;
    }
    __syncthreads();

    // ---- stage 4: build product state, fusing CZ after layer 0 ----
    #pragma unroll
    for (int l = 0; l < 16; ++l) {
        const int e = (l << 10) | t;
        c32 v = cmul(Phi[e >> 7], Plo[e & 127]);
        st[sw(e)] = csc(czsgn(e), v);
    }
    __syncthreads();

    // ---- stage 5: layers 1..3 (layer-3 CZ dropped: |psi|^2 invariant) ----
    do_layer(st, gates[1], t, false);   // CZ after layer 0 fused in build
    do_layer(st, gates[2], t, true);    // CZ after layer 1 fused into load
    // layer 3: last pass fuses the probability reduction (no writeback)
    {
        const c32 (*gl)[4] = gates[3];
        do_pass<0>(st, gl, t, true,  false, nullptr); __syncthreads();
        do_pass<1>(st, gl, t, false, false, nullptr); __syncthreads();
        do_pass<2>(st, gl, t, false, false, nullptr); __syncthreads();
        do_pass<3>(st, gl, t, false, false, nullptr); __syncthreads();
        float acc[NQ];
        #pragma unroll
        for (int w = 0; w < NQ; ++w) acc[w] = 0.f;
        do_pass<4>(st, gl, t, false, true, acc);

        // ---- stage 6: reduce to 14 expectations, layernorm ----
        #pragma unroll
        for (int w = 0; w < NQ; ++w) {
            float v = acc[w];
            #pragma unroll
            for (int off = 32; off > 0; off >>= 1) v += __shfl_down(v, off, 64);
            acc[w] = v;
        }
        const int lane = t & 63, wv = t >> 6;
        if (lane == 0) {
            #pragma unroll
            for (int w = 0; w < NQ; ++w) wred[wv][w] = acc[w];
        }
    }
    __syncthreads();
    if (t < NQ) {
        float s = 0.f;
        #pragma unroll
        for (int k = 0; k < 16; ++k) s += wred[k][t];
        lat[t] = s;
    }
    __syncthreads();
    if (t < NQ) {
        float mu = 0.f;
        #pragma unroll
        for (int k = 0; k < NQ; ++k) mu += lat[k];
        mu *= (1.0f / NQ);
        float var = 0.f;
        #pragma unroll
        for (int k = 0; k < NQ; ++k) { float dv = lat[k] - mu; var += dv*dv; }
        var *= (1.0f / NQ);
        out[b*NQ + t] = (lat[t] - mu) * rsqrtf(var + 1e-5f);
    }
}

extern "C" void kernel_launch(void* const* d_in, const int* in_sizes, int n_in,
                              void* d_out, int out_size, void* d_ws, size_t ws_size,
                              hipStream_t stream)
{
    (void)n_in; (void)d_ws; (void)ws_size; (void)out_size;
    const float* cond = (const float*)d_in[0];
    const float* Wenc = (const float*)d_in[1];
    const float* benc = (const float*)d_in[2];
    const float* wts  = (const float*)d_in[3];
    float* out = (float*)d_out;
    const int B = in_sizes[0] / NQ;   // 256
    qlg_kernel<<<dim3(B), dim3(1024), 0, stream>>>(cond, Wenc, benc, wts, out);
}

// Round 5
// 103.300 us; speedup vs baseline: 2.5900x; 1.3424x over previous
//
#include <hip/hip_runtime.h>
#include <math.h>

#define NQ    14
#define DIM   16384
#define DEPTH 4

// Packed-fp32 complex: f2 = (re, im). ext_vector ops let the backend emit
// v_pk_fma_f32 (CDNA dual-fp32) instead of scalar v_fma_f32 pairs.
typedef __attribute__((ext_vector_type(2))) float f2;
typedef __attribute__((ext_vector_type(4))) float f4;

__device__ __forceinline__ f2 cmul(f2 a, f2 b) {
    return (f2){a.x*b.x - a.y*b.y, a.x*b.y + a.y*b.x};
}
// out = u*x + v*y (complex), with pre-swapped gate forms us=(-u.i,u.r),
// vs=(-v.i,v.r): 1 pk_mul + 3 pk_fma.
__device__ __forceinline__ f2 cmac2(f2 x, f2 u, f2 us, f2 y, f2 v, f2 vs) {
    f2 r = x.xx * u;
    r += x.yy * us;
    r += y.xx * v;
    r += y.yy * vs;
    return r;
}

// LDS swizzle: bank-pair (b64) = sw(e)&15 = e[3:0] ^ e[9:6]. Pass mappings below
// spread all 64 lanes uniformly over 16 bank pairs (4 lanes/pair).
__device__ __forceinline__ int sw(int e) { return e ^ ((e >> 6) & 0xF); }

// CZ chain sign: qubit w <-> flat bit (13-w); adjacent qubit pairs are adjacent
// flat bits, so parity = popc(e & (e>>1)) & 1.
__device__ __forceinline__ float czsgn(int e) {
    return (__popc(e & (e >> 1)) & 1) ? -1.0f : 1.0f;
}

// 3-qubit passes. Thread t (10b), seq group s, group-local l (3b; 2b for pass 4):
// P0: gates q0-2   e[13:11]=l, e[10]=s,  e[9:0]=t
// P1: gates q3-5   e[13]=s, e[12:11]=t[9:8], e[10:8]=l, e[7:0]=t[7:0]
// P2: gates q6-8   e[13]=s, e[12:8]=t[9:5],  e[7:5]=l,  e[4:0]=t[4:0]
// P3: gates q9-11  e[13]=s, e[12:10]=t[9:7], e[9:6]=t[5:2], e[5]=t[6], e[4:2]=l, e[1:0]=t[1:0]
// P4: gates q12,13 e[13:12]=s, e[11:2]=t, e[1:0]=l
template<int PASS>
__device__ __forceinline__ int emap3(int t, int s, int l) {
    if (PASS == 0) return (l << 11) | (s << 10) | t;
    if (PASS == 1) return (s << 13) | ((t >> 8) << 11) | (l << 8) | (t & 255);
    if (PASS == 2) return (s << 13) | ((t >> 5) << 8) | (l << 5) | (t & 31);
    if (PASS == 3) return (s << 13) | ((t >> 7) << 10) | (((t >> 2) & 15) << 6)
                        | (((t >> 6) & 1) << 5) | (l << 2) | (t & 3);
    return (s << 12) | (t << 2) | l;
}

// Register budget: backend pins 1024-thread kernels at 64 VGPRs (rounds 1-4:
// launch_bounds / waves_per_eu / num_vgpr all ignored). Gates live in LDS and
// are fetched at point of use (b128 broadcast); amp groups of <=8 keep the
// peak live set ~45 < 64. No persistent acc[14] (see do_pass4_final).
template<int PASS>
__device__ __forceinline__ void do_pass(f2* st, const f4 (*gl)[4], int t,
                                        bool mulsign)
{
    constexpr int NS    = (PASS == 4) ? 4 : 2;
    constexpr int NL    = (PASS == 4) ? 4 : 8;
    constexpr int NG    = (PASS == 4) ? 2 : 3;
    constexpr int QBASE = (PASS == 4) ? 12 : 3 * PASS;

    #pragma unroll 1   // keep groups sequential: only NL amps live at a time
    for (int s = 0; s < NS; ++s) {
        f2 a[NL];
        #pragma unroll
        for (int l = 0; l < NL; ++l)
            a[l] = st[sw(emap3<PASS>(t, s, l))];
        if (mulsign) {  // fused CZ sign from the previous layer
            #pragma unroll
            for (int l = 0; l < NL; ++l)
                a[l] *= czsgn(emap3<PASS>(t, s, l));
        }
        #pragma unroll
        for (int g = 0; g < NG; ++g) {
            const int mask = (PASS == 4) ? (2 >> g) : (4 >> g);
            // gate rows fetched as b128 from LDS (wave-uniform broadcast):
            // g0=(u00|u00s) g1=(u01|u01s) g2=(u10|u10s) g3=(u11|u11s)
            f4 g0 = gl[QBASE + g][0];
            f4 g1 = gl[QBASE + g][1];
            f4 g2 = gl[QBASE + g][2];
            f4 g3 = gl[QBASE + g][3];
            #pragma unroll
            for (int l = 0; l < NL; ++l) {
                if (l & mask) continue;
                const int j = l | mask;
                f2 x = a[l], y = a[j];
                a[l] = cmac2(x, g0.xy, g0.zw, y, g1.xy, g1.zw);
                a[j] = cmac2(x, g2.xy, g2.zw, y, g3.xy, g3.zw);
            }
        }
        #pragma unroll
        for (int l = 0; l < NL; ++l)
            st[sw(emap3<PASS>(t, s, l))] = a[l];
    }
}

// Final pass (layer 3, qubits 12-13) with fused probability reduction.
// Sign-structure factorization: e = (s<<12)|(t<<2)|l, so Z_SIGNS bits are
// s-bits (wires 0,1), t-bits (wires 2..11, THREAD-UNIFORM), l-bits (12,13).
// Only 5 accumulators needed (SU, A0, A1, B0, B1) instead of acc[14] —
// round 4's remaining 100 MB spill was acc[14] round-tripping per group.
__device__ __forceinline__ void do_pass4_final(f2* st, const f4 (*gl)[4], int t,
                                               float& SU, float& A0, float& A1,
                                               float& B0, float& B1)
{
    SU = A0 = A1 = B0 = B1 = 0.f;
    #pragma unroll 1
    for (int s = 0; s < 4; ++s) {
        f2 a[4];
        #pragma unroll
        for (int l = 0; l < 4; ++l)
            a[l] = st[sw(emap3<4>(t, s, l))];
        #pragma unroll
        for (int g = 0; g < 2; ++g) {
            const int mask = 2 >> g;
            f4 g0 = gl[12 + g][0];
            f4 g1 = gl[12 + g][1];
            f4 g2 = gl[12 + g][2];
            f4 g3 = gl[12 + g][3];
            #pragma unroll
            for (int l = 0; l < 4; ++l) {
                if (l & mask) continue;
                const int j = l | mask;
                f2 x = a[l], y = a[j];
                a[l] = cmac2(x, g0.xy, g0.zw, y, g1.xy, g1.zw);
                a[j] = cmac2(x, g2.xy, g2.zw, y, g3.xy, g3.zw);
            }
        }
        float p0 = a[0].x*a[0].x + a[0].y*a[0].y;
        float p1 = a[1].x*a[1].x + a[1].y*a[1].y;
        float p2 = a[2].x*a[2].x + a[2].y*a[2].y;
        float p3 = a[3].x*a[3].x + a[3].y*a[3].y;
        float G  = (p0 + p1) + (p2 + p3);
        SU += G;
        A0 += (s & 2) ? -G : G;            // wire 0: bit13 = s[1]
        A1 += (s & 1) ? -G : G;            // wire 1: bit12 = s[0]
        B0 += (p0 + p1) - (p2 + p3);       // wire 12: bit1 = l[1]
        B1 += (p0 - p1) + (p2 - p3);       // wire 13: bit0 = l[0]
    }
}

__device__ __forceinline__ void do_layer(f2* st, const f4 (*gl)[4], int t,
                                         bool mulsign)
{
    do_pass<0>(st, gl, t, mulsign); __syncthreads();
    do_pass<1>(st, gl, t, false);   __syncthreads();
    do_pass<2>(st, gl, t, false);   __syncthreads();
    do_pass<3>(st, gl, t, false);   __syncthreads();
    do_pass<4>(st, gl, t, false);   __syncthreads();
}

__global__ __launch_bounds__(1024)
void qlg_kernel(const float* __restrict__ cond,
                const float* __restrict__ Wenc,
                const float* __restrict__ benc,
                const float* __restrict__ wts,
                float* __restrict__ out)
{
    __shared__ f2 st[DIM];                  // 128 KB state (swizzled index)
    __shared__ f4 gates[DEPTH][NQ][4];      // per gate: (u|u_swapped) rows
    __shared__ f2 qv[NQ][2];                // per-wire product-state vectors
    __shared__ f2 Phi[128];                 // partial product, qubits 0..6
    __shared__ f2 Plo[128];                 // partial product, qubits 7..13
    __shared__ float embS[NQ];
    __shared__ float wred[16][NQ];
    __shared__ float lat[NQ];

    const int b = blockIdx.x;
    const int t = threadIdx.x;

    // ---- stage 1: embedding (SiLU) + gate matrices ----
    if (t < NQ) {
        float s = benc[t];
        #pragma unroll
        for (int k = 0; k < NQ; ++k) s += cond[b*NQ + k] * Wenc[t*NQ + k];
        embS[t] = s / (1.0f + __expf(-s));
    }
    if (t >= 64 && t < 64 + DEPTH*NQ) {
        const int gi = t - 64;
        const int d = gi / NQ, w = gi % NQ;
        const float p0 = wts[(d*NQ + w)*3 + 0];
        const float p1 = wts[(d*NQ + w)*3 + 1];
        const float p2 = wts[(d*NQ + w)*3 + 2];
        float s0, c0, s1, c1, s2, c2;
        sincosf(0.5f*p0, &s0, &c0);
        sincosf(0.5f*p1, &s1, &c1);
        sincosf(0.5f*p2, &s2, &c2);
        // U = RY(p2) * RX(p1) * RZ(p0)
        f2 e0  = (f2){c0, -s0};             // exp(-i p0/2)
        f2 e0c = (f2){c0,  s0};
        f2 is1 = (f2){0.f, -s1};            // -i sin(p1/2)
        f2 m00 = c1 * e0;
        f2 m01 = cmul(is1, e0c);
        f2 m10 = cmul(is1, e0);
        f2 m11 = c1 * e0c;
        f2 u00 = c2*m00 - s2*m10;
        f2 u01 = c2*m01 - s2*m11;
        f2 u10 = s2*m00 + c2*m10;
        f2 u11 = s2*m01 + c2*m11;
        gates[d][w][0] = (f4){u00.x, u00.y, -u00.y, u00.x};
        gates[d][w][1] = (f4){u01.x, u01.y, -u01.y, u01.x};
        gates[d][w][2] = (f4){u10.x, u10.y, -u10.y, u10.x};
        gates[d][w][3] = (f4){u11.x, u11.y, -u11.y, u11.x};
    }
    __syncthreads();

    // ---- stage 2: per-wire 2-vectors after encoding + layer 0 ----
    if (t < NQ) {
        float v = embS[t];
        float s, c;
        sincosf(0.5f*v, &s, &c);
        f2 a0 = (f2){c*c,  s*s};            // (RY RX)|0> component 0
        f2 a1 = (f2){s*c, -s*c};            // component 1
        f2 u00 = gates[0][t][0].xy, u01 = gates[0][t][1].xy;
        f2 u10 = gates[0][t][2].xy, u11 = gates[0][t][3].xy;
        qv[t][0] = cmul(u00, a0) + cmul(u01, a1);
        qv[t][1] = cmul(u10, a0) + cmul(u11, a1);
    }
    __syncthreads();

    // ---- stage 3: partial-product tables ----
    if (t < 128) {
        f2 p = qv[0][(t >> 6) & 1];
        #pragma unroll
        for (int w = 1; w <= 6; ++w) p = cmul(p, qv[w][(t >> (6 - w)) & 1]);
        Phi[t] = p;
    } else if (t < 256) {
        const int j = t - 128;
        f2 p = qv[7][(j >> 6) & 1];
        #pragma unroll
        for (int w = 8; w <= 13; ++w) p = cmul(p, qv[w][(j >> (13 - w)) & 1]);
        Plo[j] = p;
    }
    __syncthreads();

    // ---- stage 4: build product state, fusing CZ after layer 0 ----
    #pragma unroll
    for (int l = 0; l < 16; ++l) {
        const int e = (l << 10) | t;
        f2 v = cmul(Phi[e >> 7], Plo[e & 127]);
        st[sw(e)] = v * czsgn(e);
    }
    __syncthreads();

    // ---- stage 5: layers 1..3 (layer-3 CZ dropped: |psi|^2 invariant) ----
    do_layer(st, gates[1], t, false);   // CZ after layer 0 fused in build
    do_layer(st, gates[2], t, true);    // CZ after layer 1 fused into load
    {
        const f4 (*gl)[4] = gates[3];
        do_pass<0>(st, gl, t, true);  __syncthreads();  // CZ after layer 2
        do_pass<1>(st, gl, t, false); __syncthreads();
        do_pass<2>(st, gl, t, false); __syncthreads();
        do_pass<3>(st, gl, t, false); __syncthreads();
        float SU, A0, A1, B0, B1;
        do_pass4_final(st, gl, t, SU, A0, A1, B0, B1);

        // ---- stage 6: reduce to 14 expectations ----
        const int lane = t & 63, wv = t >> 6;
        #pragma unroll
        for (int w = 0; w < NQ; ++w) {
            float v;
            if      (w == 0)  v = A0;
            else if (w == 1)  v = A1;
            else if (w == 12) v = B0;
            else if (w == 13) v = B1;
            else              v = ((t >> (11 - w)) & 1) ? -SU : SU;
            #pragma unroll
            for (int off = 32; off > 0; off >>= 1) v += __shfl_down(v, off, 64);
            if (lane == 0) wred[wv][w] = v;
        }
    }
    __syncthreads();
    if (t < NQ) {
        float s = 0.f;
        #pragma unroll
        for (int k = 0; k < 16; ++k) s += wred[k][t];
        lat[t] = s;
    }
    __syncthreads();
    if (t < NQ) {
        float mu = 0.f;
        #pragma unroll
        for (int k = 0; k < NQ; ++k) mu += lat[k];
        mu *= (1.0f / NQ);
        float var = 0.f;
        #pragma unroll
        for (int k = 0; k < NQ; ++k) { float dv = lat[k] - mu; var += dv*dv; }
        var *= (1.0f / NQ);
        out[b*NQ + t] = (lat[t] - mu) * rsqrtf(var + 1e-5f);
    }
}

extern "C" void kernel_launch(void* const* d_in, const int* in_sizes, int n_in,
                              void* d_out, int out_size, void* d_ws, size_t ws_size,
                              hipStream_t stream)
{
    (void)n_in; (void)d_ws; (void)ws_size; (void)out_size;
    const float* cond = (const float*)d_in[0];
    const float* Wenc = (const float*)d_in[1];
    const float* benc = (const float*)d_in[2];
    const float* wts  = (const float*)d_in[3];
    float* out = (float*)d_out;
    const int B = in_sizes[0] / NQ;   // 256
    qlg_kernel<<<dim3(B), dim3(1024), 0, stream>>>(cond, Wenc, benc, wts, out);
}